// Round 7
// baseline (667.039 us; speedup 1.0000x reference)
//
#include <hip/hip_runtime.h>

// Action_Prediction: 3-layer MLP (relu) -> scalar logit -> per-segment softmax
// -> Gumbel-max sample. N=524288, B=4096 segments of 128 contiguous nodes.
//
// R9 == R8 resubmit (R8 bench died of container-acquisition infra failure;
// no compile/correctness/counter signal. Line audit found no race, OOB,
// misalignment, or resource overflow -> resubmitting unchanged).
//
// R8 theory: fp8-e4m3 everything -> 4 fat waves/SIMD.
// Session finding: VGPR_Count excludes AGPR. R2/R6/R7 = 108 VGPR + 128 AGPR
// acc = 236 combined -> 2 waves/SIMD, per-wave MFMA duty 12.5%, wall pinned
// at ~275us across four different inner-loop structures. R3 proved 4 waves/
// SIMD is reachable at combined<=128 but died of dup panels + fat bf16 frags.
// R8 fixes both: fp8 frags (8B = 2 VGPR), acc[2][2]=64 AGPR, wave tile
// 64 feat x 64 node, two node-phases per layer sharing one Abuf:
//   {compute p0 | bar | wb p0, compute p1 | bar | wb p1} x L0,L1; L2 -> head.
// Abuf fp8 = 33.8KB (stride 264B == 2 dwords mod 32: conflict-free-ish),
// total LDS ~37.5KB -> 4 blocks/CU (was 2). LDS bytes halve. MFMA
// 32x32x16_fp8_fp8 = bf16 rate, same step count. Accuracy: R0 tolerance
// evidence (in-segment winner error always <=127 << 10486 threshold; bf16
// passed with huge margin) -> fp8 safe.
//
// d_ws: W0t fp8 [n=256][k=128]; W1t,W2t fp8 [256][256] (n-major rows).

#define NFULL 524288
#define BSEG  4096
#define SEGSZ 128
#define DIN   128
#define HID   256
#define MROWS 128
#define KPB   264   // Abuf row stride in BYTES: 66 dwords == 2 mod 32 -> free 2-way

typedef float f32x16 __attribute__((ext_vector_type(16)));

#define MFMA8(a, b, c) \
  __builtin_amdgcn_mfma_f32_32x32x16_fp8_fp8((a), (b), (c), 0, 0, 0)

// pack 4 floats -> 4 fp8 e4m3 bytes (memory order a,b,c,d)
__device__ __forceinline__ unsigned pk4(float a, float b, float c, float d) {
  int v = __builtin_amdgcn_cvt_pk_fp8_f32(a, b, 0, false);   // bytes 0,1
  v = __builtin_amdgcn_cvt_pk_fp8_f32(c, d, v, true);        // bytes 2,3
  return (unsigned)v;
}

// ------------------------------------------------- weight transpose+convert
// W0t [n=256][k=128] fp8 (32 words/row); W1t/W2t [256][256] (64 words/row).
__global__ __launch_bounds__(256) void convert_weights(
    const float* __restrict__ W0, const float* __restrict__ W1,
    const float* __restrict__ W2,
    unsigned* __restrict__ W0t, unsigned* __restrict__ W1t,
    unsigned* __restrict__ W2t) {
  const int tid = blockIdx.x * 256 + threadIdx.x;
  if (tid < 8192) {                      // W0 [k=128][n=256] -> W0t[n][k]
    const int n = tid >> 5, k4 = (tid & 31) * 4;
    W0t[tid] = pk4(W0[k4 * 256 + n], W0[(k4 + 1) * 256 + n],
                   W0[(k4 + 2) * 256 + n], W0[(k4 + 3) * 256 + n]);
  } else if (tid < 24576) {              // W1 [256][256]
    const int u = tid - 8192;
    const int n = u >> 6, k4 = (u & 63) * 4;
    W1t[u] = pk4(W1[k4 * 256 + n], W1[(k4 + 1) * 256 + n],
                 W1[(k4 + 2) * 256 + n], W1[(k4 + 3) * 256 + n]);
  } else if (tid < 40960) {              // W2 [256][256]
    const int u = tid - 24576;
    const int n = u >> 6, k4 = (u & 63) * 4;
    W2t[u] = pk4(W2[k4 * 256 + n], W2[(k4 + 1) * 256 + n],
                 W2[(k4 + 2) * 256 + n], W2[(k4 + 3) * 256 + n]);
  }
}

// ---------------------------------------------------------------- MFMA core
// 32x32x16 fp8: A-frag lane l: A[m=l&31][k=(l>>5)*8+j], 8 bytes (i64).
// B-frag lane l: B[k=(l>>5)*8+j][n=l&31] -> Abuf row (node), contiguous k.
// C/D lane l, reg r: col=l&31 (node), row=(r&3)+8*(r>>2)+4*(l>>5) (feat)
// [guide §3 m74/m101; C/D layout dtype-independent m121-128; bf16 analog
// verified end-to-end by R6 passing].

template<int K>
__device__ __forceinline__ void phase_mm(
    const unsigned char* Abuf, const unsigned char* __restrict__ Wt,
    const float* __restrict__ bias, int w, int p, int l31, int h,
    f32x16 (&acc)[2][2]) {
  constexpr int S = K / 16;
  #pragma unroll
  for (int mt = 0; mt < 2; ++mt) {
    f32x16 c;
    #pragma unroll
    for (int g = 0; g < 4; ++g) {
      const float4 bv = *(const float4*)&bias[w * 64 + mt * 32 + 8 * g + 4 * h];
      c[4 * g + 0] = bv.x; c[4 * g + 1] = bv.y;
      c[4 * g + 2] = bv.z; c[4 * g + 3] = bv.w;
    }
    acc[mt][0] = c; acc[mt][1] = c;
  }
  const unsigned char* Wb = Wt + (size_t)(w * 64 + l31) * K + h * 8;
  const unsigned char* Ab = Abuf + (size_t)(p * 64 + l31) * KPB + h * 8;

  long a0 = *(const long*)(Wb);
  long a1 = *(const long*)(Wb + 32 * K);
  long b0 = *(const long*)(Ab);
  long b1 = *(const long*)(Ab + 32 * KPB);
  #pragma unroll
  for (int s = 0; s < S; ++s) {
    long an0, an1, bn0, bn1;
    if (s + 1 < S) {                     // 1-step prefetch (A: L1/L2, B: LDS)
      an0 = *(const long*)(Wb + (s + 1) * 16);
      an1 = *(const long*)(Wb + 32 * K + (s + 1) * 16);
      bn0 = *(const long*)(Ab + (s + 1) * 16);
      bn1 = *(const long*)(Ab + 32 * KPB + (s + 1) * 16);
    }
    __builtin_amdgcn_s_setprio(1);
    acc[0][0] = MFMA8(a0, b0, acc[0][0]);
    acc[1][0] = MFMA8(a1, b0, acc[1][0]);
    acc[0][1] = MFMA8(a0, b1, acc[0][1]);
    acc[1][1] = MFMA8(a1, b1, acc[1][1]);
    __builtin_amdgcn_s_setprio(0);
    if (s + 1 < S) { a0 = an0; a1 = an1; b0 = bn0; b1 = bn1; }
  }
}

// writeback: lane holds 4 consecutive feats (8g+4h..+3) at fixed node ->
// one 4B fp8 word: 16 ds_write_b32/thread/phase.
__device__ __forceinline__ void wb_phase(
    unsigned char* Abuf, int w, int p, int l31, int h,
    const f32x16 (&acc)[2][2]) {
  #pragma unroll
  for (int nt = 0; nt < 2; ++nt) {
    const int node = p * 64 + nt * 32 + l31;
    #pragma unroll
    for (int mt = 0; mt < 2; ++mt)
      #pragma unroll
      for (int g = 0; g < 4; ++g) {
        const int feat = w * 64 + mt * 32 + 8 * g + 4 * h;
        *(unsigned*)&Abuf[node * KPB + feat] = pk4(
            fmaxf(acc[mt][nt][4 * g + 0], 0.f),
            fmaxf(acc[mt][nt][4 * g + 1], 0.f),
            fmaxf(acc[mt][nt][4 * g + 2], 0.f),
            fmaxf(acc[mt][nt][4 * g + 3], 0.f));
      }
  }
}

// head partial: logit contribution of this wave's 64 feats for phase nodes.
__device__ __forceinline__ void head_phase(
    float (*Lpart)[MROWS], const float* WfS, int w, int p, int l31, int h,
    const f32x16 (&acc)[2][2]) {
  #pragma unroll
  for (int nt = 0; nt < 2; ++nt) {
    float sv = 0.f;
    #pragma unroll
    for (int mt = 0; mt < 2; ++mt)
      #pragma unroll
      for (int g = 0; g < 4; ++g) {
        const float4 wf = *(const float4*)&WfS[w * 64 + mt * 32 + 8 * g + 4 * h];
        sv = fmaf(fmaxf(acc[mt][nt][4 * g + 0], 0.f), wf.x, sv);
        sv = fmaf(fmaxf(acc[mt][nt][4 * g + 1], 0.f), wf.y, sv);
        sv = fmaf(fmaxf(acc[mt][nt][4 * g + 2], 0.f), wf.z, sv);
        sv = fmaf(fmaxf(acc[mt][nt][4 * g + 3], 0.f), wf.w, sv);
      }
    sv += __shfl_xor(sv, 32, 64);        // combine the two feat-halves (h)
    if (h == 0) Lpart[w][p * 64 + nt * 32 + l31] = sv;
  }
}

// ------------------------------------------------------------------ sampling
__device__ __forceinline__ void threefry2x32_42(unsigned x0, unsigned x1,
                                                unsigned& o0, unsigned& o1) {
  const unsigned ks0 = 0u, ks1 = 42u;
  const unsigned ks2 = ks0 ^ ks1 ^ 0x1BD11BDAu;
  x0 += ks0; x1 += ks1;
#define TF_R(r) { x0 += x1; x1 = (x1 << (r)) | (x1 >> (32 - (r))); x1 ^= x0; }
  TF_R(13) TF_R(15) TF_R(26) TF_R(6)   x0 += ks1; x1 += ks2 + 1u;
  TF_R(17) TF_R(29) TF_R(16) TF_R(24)  x0 += ks2; x1 += ks0 + 2u;
  TF_R(13) TF_R(15) TF_R(26) TF_R(6)   x0 += ks0; x1 += ks1 + 3u;
  TF_R(17) TF_R(29) TF_R(16) TF_R(24)  x0 += ks1; x1 += ks2 + 4u;
  TF_R(13) TF_R(15) TF_R(26) TF_R(6)   x0 += ks2; x1 += ks0 + 5u;
#undef TF_R
  o0 = x0; o1 = x1;
}

// -------------------------------------------------------------- fused kernel
__global__ __launch_bounds__(256, 4) void mlp_fused(
    const float* __restrict__ X,
    const unsigned char* __restrict__ W0t,
    const unsigned char* __restrict__ W1t,
    const unsigned char* __restrict__ W2t,
    const float* __restrict__ b0, const float* __restrict__ b1,
    const float* __restrict__ b2,
    const float* __restrict__ Wf, const float* __restrict__ bfp,
    float* __restrict__ out) {
  __shared__ alignas(8) unsigned char Abuf[MROWS * KPB];  // 33.8 KB
  __shared__ float WfS[HID];
  __shared__ float Lpart[4][MROWS];
  __shared__ float red2[2];
  __shared__ float smax_sh[2];
  __shared__ int   sidx_sh[2];
  __shared__ float probs_sh[SEGSZ];

  const int tid  = threadIdx.x;
  const int lane = tid & 63;
  const int w    = tid >> 6;     // 0..3: feature group (64 feats)
  const int l31  = lane & 31;
  const int h    = lane >> 5;
  const size_t row0 = (size_t)blockIdx.x * MROWS;

  if (tid < HID) WfS[tid] = Wf[tid];

  // stage X fp32 -> fp8: 16 x {coalesced float4 read, 4B ds_write}
  {
    const float* Xb = X + row0 * DIN;
    #pragma unroll
    for (int it = 0; it < 16; ++it) {
      const int idx = tid * 4 + it * 1024;
      const int r = idx >> 7, k = idx & 127;
      const float4 v = *(const float4*)&Xb[idx];
      *(unsigned*)&Abuf[r * KPB + k] = pk4(v.x, v.y, v.z, v.w);
    }
  }
  __syncthreads();

  f32x16 acc[2][2];
  // L0 (K=128): p0 reads X rows 0-63; bar; wb p0 overwrites rows 0-63 while
  // p1 computes from rows 64-127 (disjoint). Same ping-pong for L1.
  phase_mm<DIN>(Abuf, W0t, b0, w, 0, l31, h, acc);
  __syncthreads();
  wb_phase(Abuf, w, 0, l31, h, acc);
  phase_mm<DIN>(Abuf, W0t, b0, w, 1, l31, h, acc);
  __syncthreads();
  wb_phase(Abuf, w, 1, l31, h, acc);
  // L1 (K=256): p0 reads rows 0-63 (all waves' L0-wb-p0 landed before bar 2)
  phase_mm<HID>(Abuf, W1t, b1, w, 0, l31, h, acc);
  __syncthreads();
  wb_phase(Abuf, w, 0, l31, h, acc);
  phase_mm<HID>(Abuf, W1t, b1, w, 1, l31, h, acc);
  __syncthreads();
  wb_phase(Abuf, w, 1, l31, h, acc);
  // L2 (K=256): no writeback, head partials straight from regs.
  phase_mm<HID>(Abuf, W2t, b2, w, 0, l31, h, acc);
  __syncthreads();     // ensures all waves' L1-wb-p1 (rows 64-127) visible
  head_phase(Lpart, WfS, w, 0, l31, h, acc);
  phase_mm<HID>(Abuf, W2t, b2, w, 1, l31, h, acc);
  head_phase(Lpart, WfS, w, 1, l31, h, acc);
  __syncthreads();

  // fused per-segment softmax + Gumbel-max (segment == this block's 128 rows)
  float e = 0.f, prob = 0.f;
  if (tid < SEGSZ) {
    const float lg = Lpart[0][tid] + Lpart[1][tid] + Lpart[2][tid] +
                     Lpart[3][tid] + bfp[0];
    e = expf(lg);
    float v = e;
    #pragma unroll
    for (int off = 32; off >= 1; off >>= 1) v += __shfl_xor(v, off, 64);
    if ((tid & 63) == 0) red2[tid >> 6] = v;
  }
  __syncthreads();
  if (tid < SEGSZ) {
    const float S = red2[0] + red2[1];
    prob = e / S;
    probs_sh[tid] = prob;
    unsigned o0, o1;
    threefry2x32_42(0u, (unsigned)(row0 + (size_t)tid), o0, o1);
    const float f = __uint_as_float(0x3f800000u | (o0 >> 9)) - 1.0f;
    const float u = fmaxf(1e-20f, f + 1e-20f);
    const float g = -logf(-logf(u));
    float ms = logf(prob) + g;
    int   mi = (int)row0 + tid;
    #pragma unroll
    for (int off = 1; off < 64; off <<= 1) {
      const float os = __shfl_xor(ms, off, 64);
      const int   oi = __shfl_xor(mi, off, 64);
      if (os > ms || (os == ms && oi > mi)) { ms = os; mi = oi; }
    }
    if ((tid & 63) == 0) { smax_sh[tid >> 6] = ms; sidx_sh[tid >> 6] = mi; }
  }
  __syncthreads();
  if (tid == 0) {
    const float s0 = smax_sh[0], s1 = smax_sh[1];
    const int   i0 = sidx_sh[0], i1 = sidx_sh[1];
    const int win = (s1 > s0 || (s1 == s0 && i1 > i0)) ? i1 : i0;
    const int s = blockIdx.x;
    out[s]            = probs_sh[win - (int)row0];
    out[BSEG + s]     = (float)(win - (int)row0);
    out[2 * BSEG + s] = (float)win;
  }
}

extern "C" void kernel_launch(void* const* d_in, const int* in_sizes, int n_in,
                              void* d_out, int out_size, void* d_ws, size_t ws_size,
                              hipStream_t stream) {
  const float* X  = (const float*)d_in[0];
  const float* W0 = (const float*)d_in[1];
  const float* b0 = (const float*)d_in[2];
  const float* W1 = (const float*)d_in[3];
  const float* b1 = (const float*)d_in[4];
  const float* W2 = (const float*)d_in[5];
  const float* b2 = (const float*)d_in[6];
  const float* Wf = (const float*)d_in[7];
  const float* bf = (const float*)d_in[8];

  unsigned* W0t = (unsigned*)d_ws;       // 8192 words (32 KB)
  unsigned* W1t = W0t + 8192;            // 16384 words (64 KB)
  unsigned* W2t = W1t + 16384;           // 16384 words (64 KB)
  float* out = (float*)d_out;

  convert_weights<<<160, 256, 0, stream>>>(W0, W1, W2, W0t, W1t, W2t);
  mlp_fused<<<BSEG, 256, 0, stream>>>(
      X, (const unsigned char*)W0t, (const unsigned char*)W1t,
      (const unsigned char*)W2t, b0, b1, b2, Wf, bf, out);
}